// Round 1
// baseline (210.263 us; speedup 1.0000x reference)
//
#include <hip/hip_runtime.h>

#define SQ   2048
#define DH   64
#define NH   12
#define NBH  24
#define LDK  72   // padded LDS row stride (bf16 elems): 144B, breaks b128 bank clustering

typedef __attribute__((ext_vector_type(8))) short short8;
typedef __attribute__((ext_vector_type(4))) float f32x4;

__device__ __forceinline__ unsigned short f2bf(float x) {
  union { float f; unsigned u; } v; v.f = x;
  return (unsigned short)((v.u + 0x7FFFu + ((v.u >> 16) & 1u)) >> 16);
}

// P1: Qb = bf16(Q * 0.125), Kb = bf16(K)  (flat copy, float4 in / ushort4 out)
__global__ void prep_qk(const float* __restrict__ Q, const float* __restrict__ K,
                        unsigned short* __restrict__ Qb, unsigned short* __restrict__ Kb,
                        int n4) {
  int i = blockIdx.x * blockDim.x + threadIdx.x;
  if (i >= n4) return;
  float4 q = ((const float4*)Q)[i];
  float4 k = ((const float4*)K)[i];
  ushort4 qo, ko;
  qo.x = f2bf(q.x * 0.125f); qo.y = f2bf(q.y * 0.125f);
  qo.z = f2bf(q.z * 0.125f); qo.w = f2bf(q.w * 0.125f);
  ko.x = f2bf(k.x); ko.y = f2bf(k.y); ko.z = f2bf(k.z); ko.w = f2bf(k.w);
  ((ushort4*)Qb)[i] = qo;
  ((ushort4*)Kb)[i] = ko;
}

// P2: Vt[bh][d][s] = bf16(V[bh][s][d]) — LDS transpose, coalesced in and out.
__global__ void prep_v(const float* __restrict__ V, unsigned short* __restrict__ Vt) {
  __shared__ float T[64 * 65];   // stride 65 dwords -> conflict-free column gathers
  int bx = blockIdx.x;
  int bh = bx >> 5, st = bx & 31;
  int tid = threadIdx.x;
  int s0 = st * 64;
  int c4 = (tid & 15) * 4, r0 = tid >> 4;
#pragma unroll
  for (int it = 0; it < 4; ++it) {
    int r = r0 + 16 * it;
    float4 v = *(const float4*)(V + ((size_t)(bh * SQ + s0 + r)) * DH + c4);
    T[r * 65 + c4 + 0] = v.x; T[r * 65 + c4 + 1] = v.y;
    T[r * 65 + c4 + 2] = v.z; T[r * 65 + c4 + 3] = v.w;
  }
  __syncthreads();
#pragma unroll
  for (int it = 0; it < 2; ++it) {
    int cc = tid + 256 * it;          // 512 chunks of 8
    int d = cc >> 3, c8 = (cc & 7) * 8;
    short8 o;
#pragma unroll
    for (int j = 0; j < 8; ++j) o[j] = (short)f2bf(T[(c8 + j) * 65 + d]);
    *(short8*)(Vt + ((size_t)(bh * 64 + d)) * SQ + s0 + c8) = o;
  }
}

// P3: bit-pack mask: mbits[b*S + q][word] (64 words of 32 bits per row)
__global__ void prep_mask(const int* __restrict__ mask, unsigned* __restrict__ mbits) {
  int g = (blockIdx.x * blockDim.x + threadIdx.x) >> 6;  // wave id, 131072 total
  int lane = threadIdx.x & 63;
  int seg = g & 31, row = g >> 5;                        // row in [0, 4096)
  int v = mask[(size_t)row * SQ + seg * 64 + lane];
  unsigned long long bits = __ballot(v != 0);
  if (lane == 0) {
    mbits[row * 64 + seg * 2]     = (unsigned)bits;
    mbits[row * 64 + seg * 2 + 1] = (unsigned)(bits >> 32);
  }
}

// Main flash-attention kernel: 1 block = (b,h, 64 q-rows), 4 waves x 16 rows.
__global__ __launch_bounds__(256) void attn_kernel(
    const unsigned short* __restrict__ Qb, const unsigned short* __restrict__ Kb,
    const unsigned short* __restrict__ Vt, const unsigned* __restrict__ mbits,
    float* __restrict__ Out) {
  __shared__ unsigned short Kt [64 * LDK];
  __shared__ unsigned short Vtl[64 * LDK];
  __shared__ unsigned short Pt [4 * 16 * LDK];

  int bx = blockIdx.x;
  int bh = bx % NBH, qt = bx / NBH;     // bh-inner: same-qt blocks share mask rows
  int b  = bh / NH;
  int tid = threadIdx.x;
  int lane = tid & 63, w = tid >> 6;
  int m = lane & 15, quad = lane >> 4;
  int qrow_base = qt * 64 + w * 16;

  // Q A-frags: A[m=lane&15][k=quad*8+j (+32)]
  const unsigned short* qptr = Qb + ((size_t)(bh * SQ + qrow_base + m)) * DH + quad * 8;
  short8 qf0 = *(const short8*)(qptr);
  short8 qf1 = *(const short8*)(qptr + 32);

  f32x4 acc[4];
  float mrun[4], lrun[4];
#pragma unroll
  for (int t = 0; t < 4; ++t) acc[t] = (f32x4){0.f, 0.f, 0.f, 0.f};
#pragma unroll
  for (int r = 0; r < 4; ++r) { mrun[r] = -3e9f; lrun[r] = 0.f; }

  for (int nt = 0; nt < SQ / 64; ++nt) {
    int k0 = nt * 64;
    // ---- stage K tile (row-major) and Vt tile (d-major) into LDS ----
#pragma unroll
    for (int it = 0; it < 2; ++it) {
      int cc = tid + 256 * it;
      int rr = cc >> 3, c8 = (cc & 7) * 8;
      short8 kv = *(const short8*)(Kb + ((size_t)(bh * SQ + k0 + rr)) * DH + c8);
      short8 vv = *(const short8*)(Vt + ((size_t)(bh * 64 + rr)) * SQ + k0 + c8);
      *(short8*)&Kt [rr * LDK + c8] = kv;
      *(short8*)&Vtl[rr * LDK + c8] = vv;
    }
    __syncthreads();

    // ---- S = Q K^T  (4 n-tiles of 16 k-cols, 2 k-chunks each) ----
    f32x4 s[4];
#pragma unroll
    for (int t = 0; t < 4; ++t) {
      f32x4 a = (f32x4){0.f, 0.f, 0.f, 0.f};
      short8 b0 = *(const short8*)&Kt[(t * 16 + m) * LDK + quad * 8];
      a = __builtin_amdgcn_mfma_f32_16x16x32_bf16(qf0, b0, a, 0, 0, 0);
      short8 b1 = *(const short8*)&Kt[(t * 16 + m) * LDK + 32 + quad * 8];
      a = __builtin_amdgcn_mfma_f32_16x16x32_bf16(qf1, b1, a, 0, 0, 0);
      s[t] = a;
    }

    // ---- mask + online softmax (C-layout: row=quad*4+r, col=t*16+m) ----
    float lg[4][4];
#pragma unroll
    for (int r = 0; r < 4; ++r) {
      int qg = qrow_base + quad * 4 + r;
      uint2 mw = *(const uint2*)(mbits + (size_t)(b * SQ + qg) * 64 + nt * 2);
      unsigned wsel[2] = {mw.x, mw.y};
#pragma unroll
      for (int t = 0; t < 4; ++t) {
        unsigned bitv = (wsel[t >> 1] >> ((t & 1) * 16 + m)) & 1u;
        lg[t][r] = bitv ? s[t][r] : -1e9f;
      }
    }
    float rmax[4], rsum[4];
#pragma unroll
    for (int r = 0; r < 4; ++r)
      rmax[r] = fmaxf(fmaxf(lg[0][r], lg[1][r]), fmaxf(lg[2][r], lg[3][r]));
#pragma unroll
    for (int off = 1; off < 16; off <<= 1)
#pragma unroll
      for (int r = 0; r < 4; ++r)
        rmax[r] = fmaxf(rmax[r], __shfl_xor(rmax[r], off, 64));
    float alpha[4];
#pragma unroll
    for (int r = 0; r < 4; ++r) {
      float mnew = fmaxf(mrun[r], rmax[r]);
      alpha[r] = __expf(mrun[r] - mnew);
      mrun[r] = mnew;
    }
    float p[4][4];
#pragma unroll
    for (int t = 0; t < 4; ++t)
#pragma unroll
      for (int r = 0; r < 4; ++r)
        p[t][r] = __expf(lg[t][r] - mrun[r]);
#pragma unroll
    for (int r = 0; r < 4; ++r)
      rsum[r] = (p[0][r] + p[1][r]) + (p[2][r] + p[3][r]);
#pragma unroll
    for (int off = 1; off < 16; off <<= 1)
#pragma unroll
      for (int r = 0; r < 4; ++r)
        rsum[r] += __shfl_xor(rsum[r], off, 64);
#pragma unroll
    for (int r = 0; r < 4; ++r) lrun[r] = lrun[r] * alpha[r] + rsum[r];
#pragma unroll
    for (int t = 0; t < 4; ++t)
#pragma unroll
      for (int r = 0; r < 4; ++r) acc[t][r] *= alpha[r];

    // ---- P: C-layout -> A-layout via per-wave LDS round trip ----
    unsigned short* pw = Pt + w * 16 * LDK;
#pragma unroll
    for (int t = 0; t < 4; ++t)
#pragma unroll
      for (int r = 0; r < 4; ++r)
        pw[(quad * 4 + r) * LDK + t * 16 + m] = f2bf(p[t][r]);
    // (same-wave producer/consumer: lgkmcnt ordering, no barrier needed)

    // ---- O += P V  (B-frag from transposed V: Vt[d=lane&15+16t][k]) ----
#pragma unroll
    for (int kk = 0; kk < 2; ++kk) {
      short8 pa = *(const short8*)&Pt[w * 16 * LDK + m * LDK + kk * 32 + quad * 8];
#pragma unroll
      for (int t = 0; t < 4; ++t) {
        short8 vb = *(const short8*)&Vtl[(t * 16 + m) * LDK + kk * 32 + quad * 8];
        acc[t] = __builtin_amdgcn_mfma_f32_16x16x32_bf16(pa, vb, acc[t], 0, 0, 0);
      }
    }
    __syncthreads();
  }

  // ---- epilogue: normalize, fp32 store ----
#pragma unroll
  for (int r = 0; r < 4; ++r) {
    float inv = 1.0f / lrun[r];
    int qg = qrow_base + quad * 4 + r;
    float* op = Out + ((size_t)(bh * SQ + qg)) * DH + m;
#pragma unroll
    for (int t = 0; t < 4; ++t) op[t * 16] = acc[t][r] * inv;
  }
}

extern "C" void kernel_launch(void* const* d_in, const int* in_sizes, int n_in,
                              void* d_out, int out_size, void* d_ws, size_t ws_size,
                              hipStream_t stream) {
  const float* Q = (const float*)d_in[0];
  const float* K = (const float*)d_in[1];
  const float* V = (const float*)d_in[2];
  const int*   M = (const int*)d_in[3];
  float* Out = (float*)d_out;

  size_t NB = (size_t)NBH * SQ * DH;            // 3,145,728 elems per tensor
  unsigned short* Qb = (unsigned short*)d_ws;   // ws layout: Qb | Kb | Vt | mbits
  unsigned short* Kb = Qb + NB;
  unsigned short* Vt = Kb + NB;
  unsigned* mbits = (unsigned*)(Vt + NB);       // 4096 rows * 64 words = 1 MB

  prep_qk<<<(int)(NB / 4 / 256), 256, 0, stream>>>(Q, K, Qb, Kb, (int)(NB / 4));
  prep_v<<<NBH * (SQ / 64), 256, 0, stream>>>(V, Vt);
  prep_mask<<<(2 * SQ * (SQ / 64)) / 4, 256, 0, stream>>>(M, mbits);
  attn_kernel<<<NBH * (SQ / 64), 256, 0, stream>>>(Qb, Kb, Vt, mbits, Out);
}